// Round 8
// baseline (676.375 us; speedup 1.0000x reference)
//
#include <hip/hip_runtime.h>
#include <hip/hip_fp16.h>
#include <math.h>

// Longformer global attention, fixed shapes: B=2,H=12,S=2048,D=64,N_GLOBAL=128.
// ROUND-8: DIAGNOSTIC SPLIT into three dispatches so rocprof attributes time
// per role (4 schedules all pinned at ~277us; aggregate counters can't say
// whether B / A / store-stream owns it).
//   kernel_B: 192 blocks — full 2048-key online-softmax attn for q<128 (verbatim).
//   kernel_A: 3072 blocks — 128-key softmax -> probs head + ctx (tail-zero removed).
//   kernel_Z: 2048 blocks — pure zero-fill of probs cols 128..2047, NO LDS,
//             shaped like fillBufferAligned (which hits 6.2 TB/s on this buffer).

namespace {
constexpr int BATCH = 2;
constexpr int HEADS = 12;
constexpr int SEQ   = 2048;
constexpr int DIM   = 64;
constexpr int NG    = 128;
constexpr int BHN   = BATCH * HEADS;                        // 24
constexpr long long CTX_SIZE = (long long)BHN * SEQ * DIM;  // 3,145,728
constexpr float SCALE = 0.125f;                             // 1/sqrt(64)

constexpr int NB_BLOCKS = (BHN * NG) / 16;                  // 192
constexpr int NA_BLOCKS = (BHN * SEQ) / 16;                 // 3072
constexpr int TAIL_F4   = (SEQ - NG) / 4;                   // 480 float4 per row tail
constexpr int ZROWS     = 24;                               // rows per Z block
constexpr int NZ_BLOCKS = (BHN * SEQ) / ZROWS;              // 2048
constexpr int Z_PER_THREAD = ZROWS * TAIL_F4 / 256;         // 45 float4 per thread
}

typedef float nfloat4 __attribute__((ext_vector_type(4)));

__device__ __forceinline__ float wave_max64(float x) {
#pragma unroll
    for (int off = 32; off > 0; off >>= 1) x = fmaxf(x, __shfl_xor(x, off));
    return x;
}
__device__ __forceinline__ float wave_sum64(float x) {
#pragma unroll
    for (int off = 32; off > 0; off >>= 1) x += __shfl_xor(x, off);
    return x;
}

// ---------------- Z: pure tail zero-fill, no LDS ----------------
__global__ __launch_bounds__(256) void longformer_zero(float* __restrict__ out)
{
    float* const probs_out = out + CTX_SIZE;
    const size_t row0 = (size_t)blockIdx.x * ZROWS;
    float* const base = probs_out + row0 * SEQ;
    const nfloat4 z = (nfloat4)(0.f);
#pragma unroll
    for (int s = 0; s < Z_PER_THREAD; ++s) {
        int idx = s * 256 + threadIdx.x;        // 0..11519
        int row = idx / TAIL_F4;                // 0..23 (const divisor)
        int c4  = idx - row * TAIL_F4;          // 0..479
        *reinterpret_cast<nfloat4*>(base + (size_t)row * SEQ + NG + 4 * c4) = z;
    }
}

// ---------------- A: 128-key softmax for all rows ----------------
__global__ __launch_bounds__(256) void longformer_A(
    const float* __restrict__ q, const float* __restrict__ k,
    const float* __restrict__ v, float* __restrict__ out)
{
    __shared__ float  k_lds[128][68];
    __shared__ __half p_lds[4][4][128];

    float* const ctx_out   = out;
    float* const probs_out = out + CTX_SIZE;

    const int w    = threadIdx.x >> 6;
    const int lane = threadIdx.x & 63;
    const int gq   = lane >> 4;
    const int dq   = lane & 15;

    const int ablk  = blockIdx.x;
    const int bh    = ablk >> 7;
    const int qbase = (ablk & 127) << 4;
    const int row0  = qbase + w * 4;
    const float* const qb = q + (size_t)bh * SEQ * DIM;
    const float* const kb = k + (size_t)bh * SEQ * DIM;
    const float* const vb = v + (size_t)bh * SEQ * DIM;

#pragma unroll
    for (int j = 0; j < 8; ++j) {
        int f  = threadIdx.x + j * 256;
        int g  = f >> 4;
        int ci = (f & 15) << 2;
        float4 t = *reinterpret_cast<const float4*>(kb + g * DIM + ci);
        *reinterpret_cast<float4*>(&k_lds[g][ci]) = t;
    }
    __syncthreads();

    float s0[4] = {0,0,0,0}, s1[4] = {0,0,0,0};
    const float* krow0 = &k_lds[lane][0];
    const float* krow1 = &k_lds[lane + 64][0];
#pragma unroll 4
    for (int i = 0; i < 16; ++i) {
        const float4 ka = *reinterpret_cast<const float4*>(krow0 + 4 * i);
        const float4 kc = *reinterpret_cast<const float4*>(krow1 + 4 * i);
#pragma unroll
        for (int r = 0; r < 4; ++r) {
            const float4 qv = *reinterpret_cast<const float4*>(qb + (size_t)(row0 + r) * DIM + 4 * i);
            s0[r] += qv.x * ka.x + qv.y * ka.y + qv.z * ka.z + qv.w * ka.w;
            s1[r] += qv.x * kc.x + qv.y * kc.y + qv.z * kc.z + qv.w * kc.w;
        }
    }
    float e0v[4], e1v[4];
#pragma unroll
    for (int r = 0; r < 4; ++r) {
        float a = s0[r] * SCALE, b = s1[r] * SCALE;
        float m = wave_max64(fmaxf(a, b));
        float e0 = __expf(a - m), e1 = __expf(b - m);
        float inv = 1.f / wave_sum64(e0 + e1);
        e0 *= inv; e1 *= inv;
        e0v[r] = e0; e1v[r] = e1;
        p_lds[w][r][lane]      = __float2half(e0);
        p_lds[w][r][lane + 64] = __float2half(e1);
    }

    float4 c[4];
    const bool do_ctx = (qbase >= NG);
    if (do_ctx) {
#pragma unroll
        for (int r = 0; r < 4; ++r) c[r] = make_float4(0.f, 0.f, 0.f, 0.f);
#pragma unroll 2
        for (int i = 0; i < 32; ++i) {
            const int g = 4 * i + gq;
            const float4 vv = *reinterpret_cast<const float4*>(vb + g * DIM + 4 * dq);
#pragma unroll
            for (int r = 0; r < 4; ++r) {
                const float pr = __half2float(p_lds[w][r][g]);
                c[r].x += pr * vv.x; c[r].y += pr * vv.y;
                c[r].z += pr * vv.z; c[r].w += pr * vv.w;
            }
        }
    }

#pragma unroll
    for (int r = 0; r < 4; ++r) {
        float* prow = probs_out + (size_t)(bh * SEQ + row0 + r) * SEQ;
        prow[lane]      = e0v[r];
        prow[lane + 64] = e1v[r];
    }
    if (do_ctx) {
#pragma unroll
        for (int r = 0; r < 4; ++r) {
            c[r].x += __shfl_xor(c[r].x, 16); c[r].y += __shfl_xor(c[r].y, 16);
            c[r].z += __shfl_xor(c[r].z, 16); c[r].w += __shfl_xor(c[r].w, 16);
            c[r].x += __shfl_xor(c[r].x, 32); c[r].y += __shfl_xor(c[r].y, 32);
            c[r].z += __shfl_xor(c[r].z, 32); c[r].w += __shfl_xor(c[r].w, 32);
            if (lane < 16) {
                nfloat4 cv; cv.x = c[r].x; cv.y = c[r].y; cv.z = c[r].z; cv.w = c[r].w;
                *reinterpret_cast<nfloat4*>(ctx_out + (size_t)(bh * SEQ + row0 + r) * DIM + 4 * dq) = cv;
            }
        }
    }
}

// ---------------- B: full 2048-key attention for q<128 ----------------
__global__ __launch_bounds__(256) void longformer_B(
    const float* __restrict__ q, const float* __restrict__ k,
    const float* __restrict__ v, float* __restrict__ out)
{
    __shared__ float  k_lds[128][68];
    __shared__ __half p_lds[4][4][128];

    float* const ctx_out = out;

    const int w    = threadIdx.x >> 6;
    const int lane = threadIdx.x & 63;
    const int gq   = lane >> 4;
    const int dq   = lane & 15;

    const int blk   = blockIdx.x;
    const int bh    = blk >> 3;
    const int qbase = (blk & 7) << 4;
    const int row0  = qbase + w * 4;
    const float* const qb = q + (size_t)bh * SEQ * DIM;
    const float* const kb = k + (size_t)bh * SEQ * DIM;
    const float* const vb = v + (size_t)bh * SEQ * DIM;

    float m[4], l[4];
    float4 c[4];
#pragma unroll
    for (int r = 0; r < 4; ++r) { m[r] = -INFINITY; l[r] = 0.f; c[r] = make_float4(0.f,0.f,0.f,0.f); }

    for (int t = 0; t < 16; ++t) {
        const float* kt = kb + (size_t)t * 128 * DIM;
        const float* vt = vb + (size_t)t * 128 * DIM;

        __syncthreads();
#pragma unroll
        for (int j = 0; j < 8; ++j) {
            int f  = threadIdx.x + j * 256;
            int g  = f >> 4;
            int ci = (f & 15) << 2;
            float4 tt = *reinterpret_cast<const float4*>(kt + g * DIM + ci);
            *reinterpret_cast<float4*>(&k_lds[g][ci]) = tt;
        }
        __syncthreads();

        float s0[4] = {0,0,0,0}, s1[4] = {0,0,0,0};
        const float* krow0 = &k_lds[lane][0];
        const float* krow1 = &k_lds[lane + 64][0];
#pragma unroll 4
        for (int i = 0; i < 16; ++i) {
            const float4 ka = *reinterpret_cast<const float4*>(krow0 + 4 * i);
            const float4 kc = *reinterpret_cast<const float4*>(krow1 + 4 * i);
#pragma unroll
            for (int r = 0; r < 4; ++r) {
                const float4 qv = *reinterpret_cast<const float4*>(qb + (size_t)(row0 + r) * DIM + 4 * i);
                s0[r] += qv.x * ka.x + qv.y * ka.y + qv.z * ka.z + qv.w * ka.w;
                s1[r] += qv.x * kc.x + qv.y * kc.y + qv.z * kc.z + qv.w * kc.w;
            }
        }
#pragma unroll
        for (int r = 0; r < 4; ++r) {
            float a  = s0[r] * SCALE, b = s1[r] * SCALE;
            float tm = wave_max64(fmaxf(a, b));
            float mn = fmaxf(m[r], tm);
            float corr = __expf(m[r] - mn);
            float e0 = __expf(a - mn), e1 = __expf(b - mn);
            float ts = wave_sum64(e0 + e1);
            l[r] = l[r] * corr + ts;
            c[r].x *= corr; c[r].y *= corr; c[r].z *= corr; c[r].w *= corr;
            m[r] = mn;
            p_lds[w][r][lane]      = __float2half(e0);
            p_lds[w][r][lane + 64] = __float2half(e1);
        }
#pragma unroll 2
        for (int i = 0; i < 32; ++i) {
            const int g = 4 * i + gq;
            const float4 vv = *reinterpret_cast<const float4*>(vt + g * DIM + 4 * dq);
#pragma unroll
            for (int r = 0; r < 4; ++r) {
                const float pr = __half2float(p_lds[w][r][g]);
                c[r].x += pr * vv.x; c[r].y += pr * vv.y;
                c[r].z += pr * vv.z; c[r].w += pr * vv.w;
            }
        }
    }
#pragma unroll
    for (int r = 0; r < 4; ++r) {
        c[r].x += __shfl_xor(c[r].x, 16); c[r].y += __shfl_xor(c[r].y, 16);
        c[r].z += __shfl_xor(c[r].z, 16); c[r].w += __shfl_xor(c[r].w, 16);
        c[r].x += __shfl_xor(c[r].x, 32); c[r].y += __shfl_xor(c[r].y, 32);
        c[r].z += __shfl_xor(c[r].z, 32); c[r].w += __shfl_xor(c[r].w, 32);
        const float inv = 1.f / l[r];
        c[r].x *= inv; c[r].y *= inv; c[r].z *= inv; c[r].w *= inv;
        if (lane < 16) {
            nfloat4 cv; cv.x = c[r].x; cv.y = c[r].y; cv.z = c[r].z; cv.w = c[r].w;
            *reinterpret_cast<nfloat4*>(ctx_out + (size_t)(bh * SEQ + row0 + r) * DIM + 4 * dq) = cv;
        }
    }
}

extern "C" void kernel_launch(void* const* d_in, const int* in_sizes, int n_in,
                              void* d_out, int out_size, void* d_ws, size_t ws_size,
                              hipStream_t stream) {
    const float* q = (const float*)d_in[0];
    const float* k = (const float*)d_in[1];
    const float* v = (const float*)d_in[2];
    float* out = (float*)d_out;
    hipLaunchKernelGGL(longformer_B,    dim3(NB_BLOCKS), dim3(256), 0, stream, q, k, v, out);
    hipLaunchKernelGGL(longformer_A,    dim3(NA_BLOCKS), dim3(256), 0, stream, q, k, v, out);
    hipLaunchKernelGGL(longformer_zero, dim3(NZ_BLOCKS), dim3(256), 0, stream, out);
}

// Round 9
// 664.189 us; speedup vs baseline: 1.0183x; 1.0183x over previous
//
#include <hip/hip_runtime.h>
#include <hip/hip_fp16.h>
#include <math.h>

// Longformer global attention, fixed shapes: B=2,H=12,S=2048,D=64,N_GLOBAL=128.
// ROUND-9: A restructured for streaming duty cycle:
//   - 64 q-rows per A-block (768 blocks): K panel staged once per 64 rows
//     (was 16) -> K/V HBM re-fetch / L2 pressure cut 4x; 4 passes of
//     independent post-barrier work per stage.
//   - tail zero-fill folded back into A (rounds 2-8 showed it rides free in
//     stall bubbles; separate Z cost 65us serialized).
//   - PV loop with deep unroll (8 independent loads in flight).
//   - all global stores last, no trailing barrier (background drain).
// B kept verbatim as separate dispatch for attribution: dur - 337 - A' = B.

namespace {
constexpr int BATCH = 2;
constexpr int HEADS = 12;
constexpr int SEQ   = 2048;
constexpr int DIM   = 64;
constexpr int NG    = 128;
constexpr int BHN   = BATCH * HEADS;                        // 24
constexpr long long CTX_SIZE = (long long)BHN * SEQ * DIM;  // 3,145,728
constexpr float SCALE = 0.125f;                             // 1/sqrt(64)

constexpr int NB_BLOCKS  = (BHN * NG) / 16;                 // 192
constexpr int AROWS      = 64;                              // q-rows per A block
constexpr int NA_BLOCKS  = (BHN * SEQ) / AROWS;             // 768
constexpr int TAIL_F4    = (SEQ - NG) / 4;                  // 480 float4 per row tail
constexpr int TAIL_PER_THREAD = AROWS * TAIL_F4 / 256;      // 120 float4 per thread
}

typedef float nfloat4 __attribute__((ext_vector_type(4)));

__device__ __forceinline__ float wave_max64(float x) {
#pragma unroll
    for (int off = 32; off > 0; off >>= 1) x = fmaxf(x, __shfl_xor(x, off));
    return x;
}
__device__ __forceinline__ float wave_sum64(float x) {
#pragma unroll
    for (int off = 32; off > 0; off >>= 1) x += __shfl_xor(x, off);
    return x;
}

// ---------------- A: 128-key softmax, 64 rows/block, tail-zero fused ----------------
__global__ __launch_bounds__(256) void longformer_A(
    const float* __restrict__ q, const float* __restrict__ k,
    const float* __restrict__ v, float* __restrict__ out)
{
    __shared__ float  k_lds[128][68];    // 34816 B, conflict-free b128 (17 f4 pitch)
    __shared__ __half p_lds[4][4][128];  //  4096 B, per-warp

    float* const ctx_out   = out;
    float* const probs_out = out + CTX_SIZE;

    const int w    = threadIdx.x >> 6;
    const int lane = threadIdx.x & 63;
    const int gq   = lane >> 4;
    const int dq   = lane & 15;

    const int bh    = blockIdx.x >> 5;          // 32 blocks per (b,h)
    const int qb64  = (blockIdx.x & 31) << 6;   // 64 rows per block
    const float* const qb = q + (size_t)bh * SEQ * DIM;
    const float* const kb = k + (size_t)bh * SEQ * DIM;
    const float* const vb = v + (size_t)bh * SEQ * DIM;
    const bool do_ctx = (qb64 >= NG);           // uniform per block (qb64 in {0,64} global)

    // stage K[0:128][0:64] once for 64 rows
#pragma unroll
    for (int j = 0; j < 8; ++j) {
        int f  = threadIdx.x + j * 256;
        int g  = f >> 4;
        int ci = (f & 15) << 2;
        float4 t = *reinterpret_cast<const float4*>(kb + g * DIM + ci);
        *reinterpret_cast<float4*>(&k_lds[g][ci]) = t;
    }
    __syncthreads();

    const float* krow0 = &k_lds[lane][0];
    const float* krow1 = &k_lds[lane + 64][0];

    // 4 passes x 4 rows per wave; all post-barrier work independent
    for (int p = 0; p < 4; ++p) {
        const int row0 = qb64 + (w << 4) + (p << 2);

        float s0[4] = {0,0,0,0}, s1[4] = {0,0,0,0};
#pragma unroll 4
        for (int i = 0; i < 16; ++i) {
            const float4 ka = *reinterpret_cast<const float4*>(krow0 + 4 * i);
            const float4 kc = *reinterpret_cast<const float4*>(krow1 + 4 * i);
#pragma unroll
            for (int r = 0; r < 4; ++r) {
                const float4 qv = *reinterpret_cast<const float4*>(qb + (size_t)(row0 + r) * DIM + 4 * i);
                s0[r] += qv.x * ka.x + qv.y * ka.y + qv.z * ka.z + qv.w * ka.w;
                s1[r] += qv.x * kc.x + qv.y * kc.y + qv.z * kc.z + qv.w * kc.w;
            }
        }
        float e0v[4], e1v[4];
#pragma unroll
        for (int r = 0; r < 4; ++r) {
            float a = s0[r] * SCALE, b = s1[r] * SCALE;
            float m = wave_max64(fmaxf(a, b));
            float e0 = __expf(a - m), e1 = __expf(b - m);
            float inv = 1.f / wave_sum64(e0 + e1);
            e0 *= inv; e1 *= inv;
            e0v[r] = e0; e1v[r] = e1;
            p_lds[w][r][lane]      = __float2half(e0);
            p_lds[w][r][lane + 64] = __float2half(e1);
        }

        float4 c[4];
        if (do_ctx) {
#pragma unroll
            for (int r = 0; r < 4; ++r) c[r] = make_float4(0.f, 0.f, 0.f, 0.f);
            // deep-unrolled PV: 8 independent v loads in flight
#pragma unroll 8
            for (int i = 0; i < 32; ++i) {
                const int g = 4 * i + gq;
                const float4 vv = *reinterpret_cast<const float4*>(vb + g * DIM + 4 * dq);
#pragma unroll
                for (int r = 0; r < 4; ++r) {
                    const float pr = __half2float(p_lds[w][r][g]);
                    c[r].x += pr * vv.x; c[r].y += pr * vv.y;
                    c[r].z += pr * vv.z; c[r].w += pr * vv.w;
                }
            }
        }

        // stores for this pass (head probs + ctx); no barrier
#pragma unroll
        for (int r = 0; r < 4; ++r) {
            float* prow = probs_out + (size_t)(bh * SEQ + row0 + r) * SEQ;
            prow[lane]      = e0v[r];
            prow[lane + 64] = e1v[r];
        }
        if (do_ctx) {
#pragma unroll
            for (int r = 0; r < 4; ++r) {
                c[r].x += __shfl_xor(c[r].x, 16); c[r].y += __shfl_xor(c[r].y, 16);
                c[r].z += __shfl_xor(c[r].z, 16); c[r].w += __shfl_xor(c[r].w, 16);
                c[r].x += __shfl_xor(c[r].x, 32); c[r].y += __shfl_xor(c[r].y, 32);
                c[r].z += __shfl_xor(c[r].z, 32); c[r].w += __shfl_xor(c[r].w, 32);
                if (lane < 16) {
                    nfloat4 cv; cv.x = c[r].x; cv.y = c[r].y; cv.z = c[r].z; cv.w = c[r].w;
                    *reinterpret_cast<nfloat4*>(ctx_out + (size_t)(bh * SEQ + row0 + r) * DIM + 4 * dq) = cv;
                }
            }
        }
    }

    // tail zero-fill for the block's 64 rows (pure streaming, drains at exit)
    {
        float* const tail_base = probs_out + ((size_t)bh * SEQ + qb64) * SEQ;
        const nfloat4 z = (nfloat4)(0.f);
#pragma unroll 8
        for (int s = 0; s < TAIL_PER_THREAD; ++s) {
            int idx = s * 256 + threadIdx.x;        // 0..30719
            int row = idx / TAIL_F4;                // 0..63
            int c4  = idx - row * TAIL_F4;          // 0..479
            *reinterpret_cast<nfloat4*>(tail_base + (size_t)row * SEQ + NG + 4 * c4) = z;
        }
    }
}

// ---------------- B: full 2048-key attention for q<128 (verbatim) ----------------
__global__ __launch_bounds__(256) void longformer_B(
    const float* __restrict__ q, const float* __restrict__ k,
    const float* __restrict__ v, float* __restrict__ out)
{
    __shared__ float  k_lds[128][68];
    __shared__ __half p_lds[4][4][128];

    float* const ctx_out = out;

    const int w    = threadIdx.x >> 6;
    const int lane = threadIdx.x & 63;
    const int gq   = lane >> 4;
    const int dq   = lane & 15;

    const int blk   = blockIdx.x;
    const int bh    = blk >> 3;
    const int qbase = (blk & 7) << 4;
    const int row0  = qbase + w * 4;
    const float* const qb = q + (size_t)bh * SEQ * DIM;
    const float* const kb = k + (size_t)bh * SEQ * DIM;
    const float* const vb = v + (size_t)bh * SEQ * DIM;

    float m[4], l[4];
    float4 c[4];
#pragma unroll
    for (int r = 0; r < 4; ++r) { m[r] = -INFINITY; l[r] = 0.f; c[r] = make_float4(0.f,0.f,0.f,0.f); }

    for (int t = 0; t < 16; ++t) {
        const float* kt = kb + (size_t)t * 128 * DIM;
        const float* vt = vb + (size_t)t * 128 * DIM;

        __syncthreads();
#pragma unroll
        for (int j = 0; j < 8; ++j) {
            int f  = threadIdx.x + j * 256;
            int g  = f >> 4;
            int ci = (f & 15) << 2;
            float4 tt = *reinterpret_cast<const float4*>(kt + g * DIM + ci);
            *reinterpret_cast<float4*>(&k_lds[g][ci]) = tt;
        }
        __syncthreads();

        float s0[4] = {0,0,0,0}, s1[4] = {0,0,0,0};
        const float* krow0 = &k_lds[lane][0];
        const float* krow1 = &k_lds[lane + 64][0];
#pragma unroll 4
        for (int i = 0; i < 16; ++i) {
            const float4 ka = *reinterpret_cast<const float4*>(krow0 + 4 * i);
            const float4 kc = *reinterpret_cast<const float4*>(krow1 + 4 * i);
#pragma unroll
            for (int r = 0; r < 4; ++r) {
                const float4 qv = *reinterpret_cast<const float4*>(qb + (size_t)(row0 + r) * DIM + 4 * i);
                s0[r] += qv.x * ka.x + qv.y * ka.y + qv.z * ka.z + qv.w * ka.w;
                s1[r] += qv.x * kc.x + qv.y * kc.y + qv.z * kc.z + qv.w * kc.w;
            }
        }
#pragma unroll
        for (int r = 0; r < 4; ++r) {
            float a  = s0[r] * SCALE, b = s1[r] * SCALE;
            float tm = wave_max64(fmaxf(a, b));
            float mn = fmaxf(m[r], tm);
            float corr = __expf(m[r] - mn);
            float e0 = __expf(a - mn), e1 = __expf(b - mn);
            float ts = wave_sum64(e0 + e1);
            l[r] = l[r] * corr + ts;
            c[r].x *= corr; c[r].y *= corr; c[r].z *= corr; c[r].w *= corr;
            m[r] = mn;
            p_lds[w][r][lane]      = __float2half(e0);
            p_lds[w][r][lane + 64] = __float2half(e1);
        }
#pragma unroll 2
        for (int i = 0; i < 32; ++i) {
            const int g = 4 * i + gq;
            const float4 vv = *reinterpret_cast<const float4*>(vt + g * DIM + 4 * dq);
#pragma unroll
            for (int r = 0; r < 4; ++r) {
                const float pr = __half2float(p_lds[w][r][g]);
                c[r].x += pr * vv.x; c[r].y += pr * vv.y;
                c[r].z += pr * vv.z; c[r].w += pr * vv.w;
            }
        }
    }
#pragma unroll
    for (int r = 0; r < 4; ++r) {
        c[r].x += __shfl_xor(c[r].x, 16); c[r].y += __shfl_xor(c[r].y, 16);
        c[r].z += __shfl_xor(c[r].z, 16); c[r].w += __shfl_xor(c[r].w, 16);
        c[r].x += __shfl_xor(c[r].x, 32); c[r].y += __shfl_xor(c[r].y, 32);
        c[r].z += __shfl_xor(c[r].z, 32); c[r].w += __shfl_xor(c[r].w, 32);
        const float inv = 1.f / l[r];
        c[r].x *= inv; c[r].y *= inv; c[r].z *= inv; c[r].w *= inv;
        if (lane < 16) {
            nfloat4 cv; cv.x = c[r].x; cv.y = c[r].y; cv.z = c[r].z; cv.w = c[r].w;
            *reinterpret_cast<nfloat4*>(ctx_out + (size_t)(bh * SEQ + row0 + r) * DIM + 4 * dq) = cv;
        }
    }
}

extern "C" void kernel_launch(void* const* d_in, const int* in_sizes, int n_in,
                              void* d_out, int out_size, void* d_ws, size_t ws_size,
                              hipStream_t stream) {
    const float* q = (const float*)d_in[0];
    const float* k = (const float*)d_in[1];
    const float* v = (const float*)d_in[2];
    float* out = (float*)d_out;
    hipLaunchKernelGGL(longformer_B, dim3(NB_BLOCKS), dim3(256), 0, stream, q, k, v, out);
    hipLaunchKernelGGL(longformer_A, dim3(NA_BLOCKS), dim3(256), 0, stream, q, k, v, out);
}